// Round 2
// baseline (114.123 us; speedup 1.0000x reference)
//
#include <hip/hip_runtime.h>
#include <math.h>

// ---- problem constants ----
// x: (32,32,32,32) f32; 6 layers, O=64 trees, gates/layer = 32,16,8,4,2,1
// out: (32,64,32,32) f32
// Gate network coefficients are data-independent -> precompute per launch.

struct Tabs { const int* ia[6]; const int* ib[6]; const float* w[6]; };

struct Gate { int ia, ib; float c0, c1, c2, c3; int p0, p1; }; // 32 B

__device__ __constant__ float GM[64] = {
  0,0,0,0,   0,0,0,1,   0,1,0,-1,  0,1,0,0,
  0,0,1,-1,  0,0,1,0,   0,1,1,-2,  0,1,1,-1,
  1,-1,-1,1, 1,-1,-1,2, 1,0,-1,0,  1,0,-1,1,
  1,-1,0,0,  1,-1,0,1,  1,0,0,-1,  1,0,0,0 };

// gate counts per layer: 32,16,8,4,2,1 ; gate-array bases (in gates):
//   L0:0  L1:2048  L2:3072  L3:3584  L4:3840  L5:3968 ; total 4032

__global__ __launch_bounds__(256) void precoef(Tabs t, Gate* __restrict gates) {
  int gid = blockIdx.x * 256 + threadIdx.x;
  if (gid >= 4032) return;
  int l, rel;
  if (gid < 2048)      { l = 0; rel = gid;        }
  else if (gid < 3072) { l = 1; rel = gid - 2048; }
  else if (gid < 3584) { l = 2; rel = gid - 3072; }
  else if (gid < 3840) { l = 3; rel = gid - 3584; }
  else if (gid < 3968) { l = 4; rel = gid - 3840; }
  else                 { l = 5; rel = gid - 3968; }
  int ia = t.ia[l][rel], ib = t.ib[l][rel];
  const float* wp = t.w[l] + rel * 16;
  float wv[16];
  float m = -1e30f;
  #pragma unroll
  for (int k = 0; k < 16; ++k) { wv[k] = wp[k]; m = fmaxf(m, wv[k]); }
  float e[16], s = 0.f;
  #pragma unroll
  for (int k = 0; k < 16; ++k) { e[k] = expf(wv[k] - m); s += e[k]; }
  float inv = 1.0f / s;
  float c0 = 0, c1 = 0, c2 = 0, c3 = 0;
  #pragma unroll
  for (int k = 0; k < 16; ++k) {
    float p = e[k] * inv;
    c0 += p * GM[k*4+0]; c1 += p * GM[k*4+1];
    c2 += p * GM[k*4+2]; c3 += p * GM[k*4+3];
  }
  Gate G;
  if (l == 0) {
    // decompose feature f = c*9 + ki*3 + kj into LDS offset for slab
    // xr[c][10][34] : offset = (c*10 + ki)*34 + kj ; lane adds rbase*34 + j
    int ca = ia / 9, ra = ia - ca * 9, kia = ra / 3, kja = ra - kia * 3;
    int cb = ib / 9, rb = ib - cb * 9, kib = rb / 3, kjb = rb - kib * 3;
    G.ia = (ca * 10 + kia) * 34 + kja;
    G.ib = (cb * 10 + kib) * 34 + kjb;
  } else { G.ia = ia; G.ib = ib; }
  G.c0 = c0; G.c1 = c1; G.c2 = c2; G.c3 = c3; G.p0 = 0; G.p1 = 0;
  gates[gid] = G;
}

typedef float vf32 __attribute__((ext_vector_type(32)));
typedef float vf16 __attribute__((ext_vector_type(16)));
typedef float vf8  __attribute__((ext_vector_type(8)));
typedef float vf4  __attribute__((ext_vector_type(4)));

#define RFL(v) __builtin_amdgcn_readfirstlane(v)
#define GATE(G, a, b) fmaf((G).c3, (a)*(b), fmaf((G).c2, (b), fmaf((G).c1, (a), (G).c0)))

// Block: 256 threads = 8 output rows x 32 cols of one image; grid (b, rowchunk, treechunk)
// bid bits: [2:0]=treechunk(8 trees each), [4:3]=rowchunk(8 rows each), [9:5]=batch
__global__ __launch_bounds__(256) void logic_conv(const float* __restrict x,
                                                  const Gate* __restrict gates,
                                                  float* __restrict out) {
  __shared__ float xr[10880];                    // 32 ch * 10 rows * 34 cols (43.5 KiB)
  const int bid = blockIdx.x;
  const int tc = bid & 7, rc = (bid >> 3) & 3, b = bid >> 5;
  const int r0 = rc * 8, t0 = tc * 8;
  const int tid = threadIdx.x;

  // stage input slab: rows r0-1 .. r0+8, cols -1..32, zero-padded OOB
  for (int idx = tid; idx < 10880; idx += 256) {
    int c = idx / 340, rem = idx - c * 340;
    int rr = rem / 34, sc = rem - rr * 34;
    int gr = r0 - 1 + rr, gc = sc - 1;
    float v = 0.f;
    if ((unsigned)gr < 32u && (unsigned)gc < 32u)
      v = x[((b * 32 + c) * 32 + gr) * 32 + gc];
    xr[idx] = v;
  }
  __syncthreads();

  const int rbase = tid >> 5;        // 0..7  (relative output row)
  const int j = tid & 31;            // 0..31 (output col)
  const int lbase = rbase * 34 + j;
  float* outb = out + ((b * 64 + t0) * 32 + (r0 + rbase)) * 32 + j;

  for (int t = 0; t < 8; ++t) {
    const int o = t0 + t;            // tree id, uniform across wave

    // ---- layer 0: 32 gates, operands from LDS slab ----
    const Gate* __restrict gl = gates + (o << 5);
    vf32 act;
    #pragma unroll
    for (int g = 0; g < 32; ++g) {
      Gate G = gl[g];
      float a = xr[G.ia + lbase];
      float bb = xr[G.ib + lbase];
      act[g] = GATE(G, a, bb);
    }

    // ---- layer 1: 16 gates, uniform dynamic extract from act (movrel) ----
    gl = gates + 2048 + (o << 4);
    vf16 v1;
    #pragma unroll
    for (int g = 0; g < 16; ++g) {
      Gate G = gl[g];
      float a = act[RFL(G.ia)];
      float bb = act[RFL(G.ib)];
      v1[g] = GATE(G, a, bb);
    }

    // ---- layer 2: 8 gates ----
    gl = gates + 3072 + (o << 3);
    vf8 v2;
    #pragma unroll
    for (int g = 0; g < 8; ++g) {
      Gate G = gl[g];
      float a = v1[RFL(G.ia)];
      float bb = v1[RFL(G.ib)];
      v2[g] = GATE(G, a, bb);
    }

    // ---- layer 3: 4 gates ----
    gl = gates + 3584 + (o << 2);
    vf4 v3;
    #pragma unroll
    for (int g = 0; g < 4; ++g) {
      Gate G = gl[g];
      float a = v2[RFL(G.ia)];
      float bb = v2[RFL(G.ib)];
      v3[g] = GATE(G, a, bb);
    }

    // ---- layer 4: 2 gates ----
    gl = gates + 3840 + (o << 1);
    float v4a, v4b;
    {
      Gate G = gl[0];
      float a = v3[RFL(G.ia)];
      float bb = v3[RFL(G.ib)];
      v4a = GATE(G, a, bb);
      Gate H = gl[1];
      float a2 = v3[RFL(H.ia)];
      float b2 = v3[RFL(H.ib)];
      v4b = GATE(H, a2, b2);
    }

    // ---- layer 5: 1 gate (2-way select) ----
    Gate G5 = gates[3968 + o];
    float a5 = G5.ia ? v4b : v4a;
    float b5 = G5.ib ? v4b : v4a;
    float y = GATE(G5, a5, b5);

    outb[0] = y;
    outb += 1024;                    // next tree: +32*32
  }
}

extern "C" void kernel_launch(void* const* d_in, const int* in_sizes, int n_in,
                              void* d_out, int out_size, void* d_ws, size_t ws_size,
                              hipStream_t stream) {
  const float* x = (const float*)d_in[0];
  Tabs tabs;
  for (int l = 0; l < 6; ++l) {
    tabs.ia[l] = (const int*)d_in[1 + 3 * l];
    tabs.ib[l] = (const int*)d_in[2 + 3 * l];
    tabs.w[l]  = (const float*)d_in[3 + 3 * l];
  }
  Gate* gates = (Gate*)d_ws;                    // 4032 * 32 B = 126 KiB
  precoef<<<16, 256, 0, stream>>>(tabs, gates);
  logic_conv<<<1024, 256, 0, stream>>>(x, gates, (float*)d_out);
}

// Round 3
// 66.638 us; speedup vs baseline: 1.7126x; 1.7126x over previous
//
#include <hip/hip_runtime.h>
#include <math.h>

// x: (32,32,32,32) f32; 6 layers, O=64 trees, gates/layer = 32,16,8,4,2,1
// out: (32,64,32,32) f32
// Coefs are data-independent -> precompute softmax(w)@GATE_M once per launch.
//
// Gate record (32 B, 2x int4) in d_ws, tree-major: gates[o*64 + slot], slots:
//   L0: 0..31, L1: 32..47, L2: 48..55, L3: 56..59, L4: 60..61, L5: 62
// dw0 = ia | (ib<<16)  (L0: element offsets into LDS slab; L1+: layer indices)
// dw1..4 = c0..c3 (f32)   dw5..7 pad

struct Tabs { const int* ia[6]; const int* ib[6]; const float* w[6]; };

__device__ __constant__ float GM[64] = {
  0,0,0,0,   0,0,0,1,   0,1,0,-1,  0,1,0,0,
  0,0,1,-1,  0,0,1,0,   0,1,1,-2,  0,1,1,-1,
  1,-1,-1,1, 1,-1,-1,2, 1,0,-1,0,  1,0,-1,1,
  1,-1,0,0,  1,-1,0,1,  1,0,0,-1,  1,0,0,0 };

__global__ __launch_bounds__(256) void precoef(Tabs t, int4* __restrict gates) {
  int gid = blockIdx.x * 256 + threadIdx.x;
  if (gid >= 4032) return;
  int l, rel;
  if (gid < 2048)      { l = 0; rel = gid;        }
  else if (gid < 3072) { l = 1; rel = gid - 2048; }
  else if (gid < 3584) { l = 2; rel = gid - 3072; }
  else if (gid < 3840) { l = 3; rel = gid - 3584; }
  else if (gid < 3968) { l = 4; rel = gid - 3840; }
  else                 { l = 5; rel = gid - 3968; }
  const int dl[6]  = {32, 16, 8, 4, 2, 1};
  const int ofs[6] = {0, 32, 48, 56, 60, 62};
  int o   = rel / dl[l];
  int sub = rel - o * dl[l];
  int ia = t.ia[l][rel], ib = t.ib[l][rel];
  const float* wp = t.w[l] + rel * 16;
  float wv[16];
  float m = -1e30f;
  #pragma unroll
  for (int k = 0; k < 16; ++k) { wv[k] = wp[k]; m = fmaxf(m, wv[k]); }
  float e[16], s = 0.f;
  #pragma unroll
  for (int k = 0; k < 16; ++k) { e[k] = expf(wv[k] - m); s += e[k]; }
  float inv = 1.0f / s;
  float c0 = 0, c1 = 0, c2 = 0, c3 = 0;
  #pragma unroll
  for (int k = 0; k < 16; ++k) {
    float p = e[k] * inv;
    c0 += p * GM[k*4+0]; c1 += p * GM[k*4+1];
    c2 += p * GM[k*4+2]; c3 += p * GM[k*4+3];
  }
  if (l == 0) {
    // feature f = c*9 + ki*3 + kj -> element offset into slab xr[c][6][34]
    int ca = ia / 9, ra = ia - ca * 9, kia = ra / 3, kja = ra - kia * 3;
    int cb = ib / 9, rb = ib - cb * 9, kib = rb / 3, kjb = rb - kib * 3;
    ia = (ca * 6 + kia) * 34 + kja;        // lane adds rbase*34 + j
    ib = (cb * 6 + kib) * 34 + kjb;
  }
  int slot = o * 64 + ofs[l] + sub;
  int4 ga, gb;
  ga.x = ia | (ib << 16);
  ga.y = __float_as_int(c0);
  ga.z = __float_as_int(c1);
  ga.w = __float_as_int(c2);
  gb.x = __float_as_int(c3);
  gb.y = 0; gb.z = 0; gb.w = 0;
  gates[slot * 2]     = ga;
  gates[slot * 2 + 1] = gb;
}

typedef float vf32 __attribute__((ext_vector_type(32)));
typedef float vf16 __attribute__((ext_vector_type(16)));
typedef float vf8  __attribute__((ext_vector_type(8)));
typedef float vf4  __attribute__((ext_vector_type(4)));

#define RL(v, l) __builtin_amdgcn_readlane((v), (l))

// Block: 256 threads = 4 rows x 32 cols x 2 tree-halves; 16 trees/block.
// bid bits: [1:0]=treechunk(16 trees), [4:2]=rowchunk(4 rows), [9:5]=batch
// LDS slab 32ch x 6rows x 34cols f32 = 25.5 KiB -> 4 blocks/CU, grid 1024
// = 4/CU: everything resident, single round.
__global__ __launch_bounds__(256) void logic_conv(const float* __restrict x,
                                                  const int4* __restrict gates,
                                                  float* __restrict out) {
  __shared__ float xr[6528];                     // 32*6*34
  const int bid = blockIdx.x;
  const int tc = bid & 3, rc = (bid >> 2) & 7, b = bid >> 5;
  const int r0 = rc * 4, t0 = tc * 16;
  const int tid = threadIdx.x;

  for (int idx = tid; idx < 6528; idx += 256) {
    int c = idx / 204, rem = idx - c * 204;
    int rr = rem / 34, sc = rem - rr * 34;
    int gr = r0 - 1 + rr, gc = sc - 1;
    float v = 0.f;
    if ((unsigned)gr < 32u && (unsigned)gc < 32u)
      v = x[((b * 32 + c) * 32 + gr) * 32 + gc];
    xr[idx] = v;
  }
  __syncthreads();

  const int th = tid >> 7;           // 0/1: which tree parity this half-block does
  const int rbase = (tid >> 5) & 3;  // relative output row
  const int j = tid & 31;            // output col
  const int lane = tid & 63;
  const int lbase = rbase * 34 + j;
  float* outb = out + ((b * 64 + t0) * 32 + (r0 + rbase)) * 32 + j;

  const int4* gp = gates + (t0 + th) * 128;      // 64 gates * 2 int4 per tree
  int4 ga = gp[lane * 2], gb = gp[lane * 2 + 1];

  for (int t = 0; t < 8; ++t) {
    int4 nga = ga, ngb = gb;
    if (t < 7) {                                  // prefetch next tree (o += 2)
      const int4* np = gp + 256;
      nga = np[lane * 2]; ngb = np[lane * 2 + 1];
    }

    // ---- layer 0: 32 gates, operands from LDS slab ----
    vf32 act;
    #pragma unroll
    for (int g = 0; g < 32; ++g) {
      int ip   = RL(ga.x, g);
      float c0 = __int_as_float(RL(ga.y, g));
      float c1 = __int_as_float(RL(ga.z, g));
      float c2 = __int_as_float(RL(ga.w, g));
      float c3 = __int_as_float(RL(gb.x, g));
      float a  = xr[(ip & 0xffff) + lbase];
      float bb = xr[((unsigned)ip >> 16) + lbase];
      act[g] = fmaf(c3, a * bb, fmaf(c2, bb, fmaf(c1, a, c0)));
    }

    // ---- layer 1: 16 gates, uniform dynamic extract (movrel) ----
    vf16 v1;
    #pragma unroll
    for (int g = 0; g < 16; ++g) {
      int ip   = RL(ga.x, 32 + g);
      float c0 = __int_as_float(RL(ga.y, 32 + g));
      float c1 = __int_as_float(RL(ga.z, 32 + g));
      float c2 = __int_as_float(RL(ga.w, 32 + g));
      float c3 = __int_as_float(RL(gb.x, 32 + g));
      float a  = act[ip & 0xffff];
      float bb = act[(unsigned)ip >> 16];
      v1[g] = fmaf(c3, a * bb, fmaf(c2, bb, fmaf(c1, a, c0)));
    }

    // ---- layer 2: 8 gates ----
    vf8 v2;
    #pragma unroll
    for (int g = 0; g < 8; ++g) {
      int ip   = RL(ga.x, 48 + g);
      float c0 = __int_as_float(RL(ga.y, 48 + g));
      float c1 = __int_as_float(RL(ga.z, 48 + g));
      float c2 = __int_as_float(RL(ga.w, 48 + g));
      float c3 = __int_as_float(RL(gb.x, 48 + g));
      float a  = v1[ip & 0xffff];
      float bb = v1[(unsigned)ip >> 16];
      v2[g] = fmaf(c3, a * bb, fmaf(c2, bb, fmaf(c1, a, c0)));
    }

    // ---- layer 3: 4 gates ----
    vf4 v3;
    #pragma unroll
    for (int g = 0; g < 4; ++g) {
      int ip   = RL(ga.x, 56 + g);
      float c0 = __int_as_float(RL(ga.y, 56 + g));
      float c1 = __int_as_float(RL(ga.z, 56 + g));
      float c2 = __int_as_float(RL(ga.w, 56 + g));
      float c3 = __int_as_float(RL(gb.x, 56 + g));
      float a  = v2[ip & 0xffff];
      float bb = v2[(unsigned)ip >> 16];
      v3[g] = fmaf(c3, a * bb, fmaf(c2, bb, fmaf(c1, a, c0)));
    }

    // ---- layer 4: 2 gates ----
    float v4a, v4b;
    {
      int ip   = RL(ga.x, 60);
      float c0 = __int_as_float(RL(ga.y, 60));
      float c1 = __int_as_float(RL(ga.z, 60));
      float c2 = __int_as_float(RL(ga.w, 60));
      float c3 = __int_as_float(RL(gb.x, 60));
      float a  = v3[ip & 0xffff];
      float bb = v3[(unsigned)ip >> 16];
      v4a = fmaf(c3, a * bb, fmaf(c2, bb, fmaf(c1, a, c0)));
    }
    {
      int ip   = RL(ga.x, 61);
      float c0 = __int_as_float(RL(ga.y, 61));
      float c1 = __int_as_float(RL(ga.z, 61));
      float c2 = __int_as_float(RL(ga.w, 61));
      float c3 = __int_as_float(RL(gb.x, 61));
      float a  = v3[ip & 0xffff];
      float bb = v3[(unsigned)ip >> 16];
      v4b = fmaf(c3, a * bb, fmaf(c2, bb, fmaf(c1, a, c0)));
    }

    // ---- layer 5: 1 gate (2-way select) ----
    {
      int ip   = RL(ga.x, 62);
      float c0 = __int_as_float(RL(ga.y, 62));
      float c1 = __int_as_float(RL(ga.z, 62));
      float c2 = __int_as_float(RL(ga.w, 62));
      float c3 = __int_as_float(RL(gb.x, 62));
      float a  = (ip & 0xffff) ? v4b : v4a;
      float bb = ((unsigned)ip >> 16) ? v4b : v4a;
      float y  = fmaf(c3, a * bb, fmaf(c2, bb, fmaf(c1, a, c0)));
      outb[(th + 2 * t) * 1024] = y;
    }

    gp += 256;                       // next tree for this half (o += 2)
    ga = nga; gb = ngb;
  }
}

extern "C" void kernel_launch(void* const* d_in, const int* in_sizes, int n_in,
                              void* d_out, int out_size, void* d_ws, size_t ws_size,
                              hipStream_t stream) {
  const float* x = (const float*)d_in[0];
  Tabs tabs;
  for (int l = 0; l < 6; ++l) {
    tabs.ia[l] = (const int*)d_in[1 + 3 * l];
    tabs.ib[l] = (const int*)d_in[2 + 3 * l];
    tabs.w[l]  = (const float*)d_in[3 + 3 * l];
  }
  int4* gates = (int4*)d_ws;                    // 64 trees * 64 slots * 32 B = 128 KiB
  precoef<<<16, 256, 0, stream>>>(tabs, gates);
  logic_conv<<<1024, 256, 0, stream>>>(x, gates, (float*)d_out);
}

// Round 4
// 62.849 us; speedup vs baseline: 1.8158x; 1.0603x over previous
//
#include <hip/hip_runtime.h>
#include <math.h>

// x: (32,32,32,32) f32; 6 layers, O=64 trees, gates/layer = 32,16,8,4,2,1
// out: (32,64,32,32) f32
// Coefs are data-independent -> precompute softmax(w)@GATE_M once per launch.
//
// Gate record (32 B, 2x int4) in d_ws, tree-major: gates[o*64 + slot], slots:
//   L0: 0..31, L1: 32..47, L2: 48..55, L3: 56..59, L4: 60..61, L5: 62
// dw0 = ia | (ib<<16)  (L0: element offsets into LDS slab; L1+: layer indices)
// dw1..4 = c0..c3 (f32)

struct Tabs { const int* ia[6]; const int* ib[6]; const float* w[6]; };

__device__ __constant__ float GM[64] = {
  0,0,0,0,   0,0,0,1,   0,1,0,-1,  0,1,0,0,
  0,0,1,-1,  0,0,1,0,   0,1,1,-2,  0,1,1,-1,
  1,-1,-1,1, 1,-1,-1,2, 1,0,-1,0,  1,0,-1,1,
  1,-1,0,0,  1,-1,0,1,  1,0,0,-1,  1,0,0,0 };

__global__ __launch_bounds__(256) void precoef(Tabs t, int4* __restrict gates) {
  int gid = blockIdx.x * 256 + threadIdx.x;
  if (gid >= 4032) return;
  int l, rel;
  if (gid < 2048)      { l = 0; rel = gid;        }
  else if (gid < 3072) { l = 1; rel = gid - 2048; }
  else if (gid < 3584) { l = 2; rel = gid - 3072; }
  else if (gid < 3840) { l = 3; rel = gid - 3584; }
  else if (gid < 3968) { l = 4; rel = gid - 3840; }
  else                 { l = 5; rel = gid - 3968; }
  const int dl[6]  = {32, 16, 8, 4, 2, 1};
  const int ofs[6] = {0, 32, 48, 56, 60, 62};
  int o   = rel / dl[l];
  int sub = rel - o * dl[l];
  int ia = t.ia[l][rel], ib = t.ib[l][rel];
  const float* wp = t.w[l] + rel * 16;
  float wv[16];
  float m = -1e30f;
  #pragma unroll
  for (int k = 0; k < 16; ++k) { wv[k] = wp[k]; m = fmaxf(m, wv[k]); }
  float e[16], s = 0.f;
  #pragma unroll
  for (int k = 0; k < 16; ++k) { e[k] = expf(wv[k] - m); s += e[k]; }
  float inv = 1.0f / s;
  float c0 = 0, c1 = 0, c2 = 0, c3 = 0;
  #pragma unroll
  for (int k = 0; k < 16; ++k) {
    float p = e[k] * inv;
    c0 += p * GM[k*4+0]; c1 += p * GM[k*4+1];
    c2 += p * GM[k*4+2]; c3 += p * GM[k*4+3];
  }
  if (l == 0) {
    // feature f = c*9 + ki*3 + kj -> element offset into slab xr[c][4][34]
    int ca = ia / 9, ra = ia - ca * 9, kia = ra / 3, kja = ra - kia * 3;
    int cb = ib / 9, rb = ib - cb * 9, kib = rb / 3, kjb = rb - kib * 3;
    ia = (ca * 4 + kia) * 34 + kja;        // lane adds rbase*34 + j
    ib = (cb * 4 + kib) * 34 + kjb;
  }
  int slot = o * 64 + ofs[l] + sub;
  int4 ga, gb;
  ga.x = ia | (ib << 16);
  ga.y = __float_as_int(c0);
  ga.z = __float_as_int(c1);
  ga.w = __float_as_int(c2);
  gb.x = __float_as_int(c3);
  gb.y = 0; gb.z = 0; gb.w = 0;
  gates[slot * 2]     = ga;
  gates[slot * 2 + 1] = gb;
}

typedef float vf32 __attribute__((ext_vector_type(32)));
typedef float vf16 __attribute__((ext_vector_type(16)));
typedef float vf8  __attribute__((ext_vector_type(8)));
typedef float vf4  __attribute__((ext_vector_type(4)));

#define RL(v, l) __builtin_amdgcn_readlane((v), (l))
// y = c0 + c1*a + c2*b + c3*a*b  ==  fma(c2,b, fma(a, fma(c3,b,c1), c0))
#define GATE4(a, b, c0, c1, c2, c3) \
  fmaf((c2), (b), fmaf((a), fmaf((c3), (b), (c1)), (c0)))

// Block: 256 threads = 4 waves; each wave = 64 px (2 rows x 32 cols), owns 4 trees.
// bid bits: [1:0]=treechunk(16 trees), [5:2]=rowchunk(2 rows), [10:6]=batch
// LDS slab 32ch x 4rows x 34cols f32 = 17 KiB -> 8 blocks/CU, grid 2048 = 8/CU
// x 4 waves = 32 waves/CU (100% wave cap), single round, no tail.
__global__ __launch_bounds__(256) void logic_conv(const float* __restrict x,
                                                  const int4* __restrict gates,
                                                  float* __restrict out) {
  __shared__ float xr[4352];                     // 32*4*34
  const int bid = blockIdx.x;
  const int tc = bid & 3, rc = (bid >> 2) & 15, b = bid >> 6;
  const int r0 = rc * 2;
  const int tid = threadIdx.x;

  // stage input slab: rows r0-1 .. r0+2, cols -1..32, zero-padded OOB
  for (int idx = tid; idx < 4352; idx += 256) {
    int c = idx / 136, rem = idx - c * 136;
    int rr = rem / 34, sc = rem - rr * 34;
    int gr = r0 - 1 + rr, gc = sc - 1;
    float v = 0.f;
    if ((unsigned)gr < 32u && (unsigned)gc < 32u)
      v = x[((b * 32 + c) * 32 + gr) * 32 + gc];
    xr[idx] = v;
  }
  __syncthreads();

  const int th = tid >> 6;           // 0..3: wave id -> tree subset
  const int rbase = (tid >> 5) & 1;  // relative output row
  const int j = tid & 31;            // output col
  const int lane = tid & 63;
  const int lbase = rbase * 34 + j;
  const int o0 = tc * 16 + th * 4;   // first tree for this wave
  float* outb = out + ((b * 64 + o0) * 32 + (r0 + rbase)) * 32 + j;

  const int4* gp = gates + o0 * 128;             // 64 slots * 2 int4 per tree
  int4 ga = gp[lane * 2], gb = gp[lane * 2 + 1];

  for (int t = 0; t < 4; ++t) {
    int4 nga = ga, ngb = gb;
    if (t < 3) {                                  // prefetch next tree
      const int4* np = gp + 128;
      nga = np[lane * 2]; ngb = np[lane * 2 + 1];
    }

    // ---- layer 0: 32 gates, operands from LDS slab ----
    vf32 act;
    #pragma unroll
    for (int g = 0; g < 32; ++g) {
      int ip   = RL(ga.x, g);
      float c0 = __int_as_float(RL(ga.y, g));
      float c1 = __int_as_float(RL(ga.z, g));
      float c2 = __int_as_float(RL(ga.w, g));
      float c3 = __int_as_float(RL(gb.x, g));
      float a  = xr[(ip & 0xffff) + lbase];
      float bb = xr[((unsigned)ip >> 16) + lbase];
      act[g] = GATE4(a, bb, c0, c1, c2, c3);
    }

    // ---- layer 1: 16 gates, uniform dynamic extract (movrel) ----
    vf16 v1;
    #pragma unroll
    for (int g = 0; g < 16; ++g) {
      int ip   = RL(ga.x, 32 + g);
      float c0 = __int_as_float(RL(ga.y, 32 + g));
      float c1 = __int_as_float(RL(ga.z, 32 + g));
      float c2 = __int_as_float(RL(ga.w, 32 + g));
      float c3 = __int_as_float(RL(gb.x, 32 + g));
      float a  = act[ip & 0xffff];
      float bb = act[(unsigned)ip >> 16];
      v1[g] = GATE4(a, bb, c0, c1, c2, c3);
    }

    // ---- layer 2: 8 gates ----
    vf8 v2;
    #pragma unroll
    for (int g = 0; g < 8; ++g) {
      int ip   = RL(ga.x, 48 + g);
      float c0 = __int_as_float(RL(ga.y, 48 + g));
      float c1 = __int_as_float(RL(ga.z, 48 + g));
      float c2 = __int_as_float(RL(ga.w, 48 + g));
      float c3 = __int_as_float(RL(gb.x, 48 + g));
      float a  = v1[ip & 0xffff];
      float bb = v1[(unsigned)ip >> 16];
      v2[g] = GATE4(a, bb, c0, c1, c2, c3);
    }

    // ---- layer 3: 4 gates ----
    vf4 v3;
    #pragma unroll
    for (int g = 0; g < 4; ++g) {
      int ip   = RL(ga.x, 56 + g);
      float c0 = __int_as_float(RL(ga.y, 56 + g));
      float c1 = __int_as_float(RL(ga.z, 56 + g));
      float c2 = __int_as_float(RL(ga.w, 56 + g));
      float c3 = __int_as_float(RL(gb.x, 56 + g));
      float a  = v2[ip & 0xffff];
      float bb = v2[(unsigned)ip >> 16];
      v3[g] = GATE4(a, bb, c0, c1, c2, c3);
    }

    // ---- layer 4: 2 gates ----
    float v4a, v4b;
    {
      int ip   = RL(ga.x, 60);
      float c0 = __int_as_float(RL(ga.y, 60));
      float c1 = __int_as_float(RL(ga.z, 60));
      float c2 = __int_as_float(RL(ga.w, 60));
      float c3 = __int_as_float(RL(gb.x, 60));
      float a  = v3[ip & 0xffff];
      float bb = v3[(unsigned)ip >> 16];
      v4a = GATE4(a, bb, c0, c1, c2, c3);
    }
    {
      int ip   = RL(ga.x, 61);
      float c0 = __int_as_float(RL(ga.y, 61));
      float c1 = __int_as_float(RL(ga.z, 61));
      float c2 = __int_as_float(RL(ga.w, 61));
      float c3 = __int_as_float(RL(gb.x, 61));
      float a  = v3[ip & 0xffff];
      float bb = v3[(unsigned)ip >> 16];
      v4b = GATE4(a, bb, c0, c1, c2, c3);
    }

    // ---- layer 5: 1 gate (2-way select) ----
    {
      int ip   = RL(ga.x, 62);
      float c0 = __int_as_float(RL(ga.y, 62));
      float c1 = __int_as_float(RL(ga.z, 62));
      float c2 = __int_as_float(RL(ga.w, 62));
      float c3 = __int_as_float(RL(gb.x, 62));
      float a  = (ip & 0xffff) ? v4b : v4a;
      float bb = ((unsigned)ip >> 16) ? v4b : v4a;
      outb[0] = GATE4(a, bb, c0, c1, c2, c3);
    }

    outb += 1024;                    // next tree: +32*32
    gp += 128;
    ga = nga; gb = ngb;
  }
}

extern "C" void kernel_launch(void* const* d_in, const int* in_sizes, int n_in,
                              void* d_out, int out_size, void* d_ws, size_t ws_size,
                              hipStream_t stream) {
  const float* x = (const float*)d_in[0];
  Tabs tabs;
  for (int l = 0; l < 6; ++l) {
    tabs.ia[l] = (const int*)d_in[1 + 3 * l];
    tabs.ib[l] = (const int*)d_in[2 + 3 * l];
    tabs.w[l]  = (const float*)d_in[3 + 3 * l];
  }
  int4* gates = (int4*)d_ws;                    // 64 trees * 64 slots * 32 B = 128 KiB
  precoef<<<16, 256, 0, stream>>>(tabs, gates);
  logic_conv<<<2048, 256, 0, stream>>>(x, gates, (float*)d_out);
}